// Round 9
// baseline (343.691 us; speedup 1.0000x reference)
//
#include <hip/hip_runtime.h>
#include <hip/hip_cooperative_groups.h>
#include <stdint.h>
#include <stddef.h>

namespace cg = cooperative_groups;

#define D_MODEL 1024
#define D_STATE 16
#define D_INNER 2048
#define BATCH   2
#define SEQ     1024
#define MROWS   (BATCH*SEQ)   // 2048

// chunked scan config
#define NCH 32
#define TCH (SEQ/NCH)         // 32
#define NREC (BATCH*D_INNER*D_STATE)  // 65536

// xproj k-split
#define XKS 8
#define XKC (D_INNER/XKS)     // 256

// gemm output modes
#define OM_BF16   0
#define OM_F32    1

typedef __bf16 bf16x8 __attribute__((ext_vector_type(8)));
typedef float  f32x4  __attribute__((ext_vector_type(4)));

__device__ __forceinline__ unsigned short f2bf(float f) {
    unsigned int u = __float_as_uint(f);
    u += 0x7fffu + ((u >> 16) & 1u);      // RNE
    return (unsigned short)(u >> 16);
}
__device__ __forceinline__ float bf2f(unsigned short v) {
    return __uint_as_float((unsigned int)v << 16);
}

// async global -> LDS, 16B/lane. Global addr is PER-LANE (gather); LDS dest is
// wave-uniform base + lane*16 (m104/m108).
__device__ __forceinline__ void gl_lds16(const unsigned short* g, unsigned short* l) {
    __builtin_amdgcn_global_load_lds(
        (const __attribute__((address_space(1))) unsigned int*)g,
        (__attribute__((address_space(3))) unsigned int*)l, 16, 0, 0);
}

// ---------------- fused fp32 -> bf16 conversions -------------------------------
__global__ void cvt_all_kernel(const float* __restrict__ x,
                               const float* __restrict__ w1,
                               const float* __restrict__ w2,
                               const float* __restrict__ xw,
                               unsigned short* __restrict__ xb,
                               unsigned short* __restrict__ wbi,
                               unsigned short* __restrict__ wbo,
                               unsigned short* __restrict__ wbp) {
    int blk = blockIdx.x, tid = threadIdx.x;
    if (blk < 8192) {
        const float* src; unsigned short* dst; int i;
        if (blk < 2048)      { src = x;  dst = xb;  i = blk * 1024 + tid * 4; }
        else if (blk < 6144) { src = w1; dst = wbi; i = (blk - 2048) * 1024 + tid * 4; }
        else                 { src = w2; dst = wbo; i = (blk - 6144) * 1024 + tid * 4; }
        float4 v = *(const float4*)(src + i);
        ushort4 o;
        o.x = f2bf(v.x); o.y = f2bf(v.y); o.z = f2bf(v.z); o.w = f2bf(v.w);
        *(ushort4*)(dst + i) = o;
    } else {
        int id = (blk - 8192) * 256 + tid;          // 0..65535
        wbp[id] = (id < 17 * D_INNER) ? f2bf(xw[id]) : (unsigned short)0;
    }
}

// ---------------- bf16 MFMA GEMM, BK=64 dual-panel LDS -------------------------
// C[m,n] = sum_k A[m,k]*Bw[n,k]. Tile 128 x NT, 256 thr (4 waves 2x2).
// A: 16 chunks/iter, B: NT/8 chunks/iter. SPLITK2: gridDim.z==2, partials.
// (R7: atomic split-K combine cost ~10us — partials+reduce wins.
//  R8: XCD supertile swizzle was neutral — operands are L3-resident; removed.)
template<int NT, bool SPLITK2, int OM>
__global__ void gemm_bf16_kernel(const unsigned short* __restrict__ A,
                                 const unsigned short* __restrict__ Bw,
                                 void* __restrict__ Cv,
                                 int M, int N, int K) {
    constexpr int NTW = NT / 32;                 // n-frags per wave (4 or 2)
    constexpr int BCH = NT / 8;                  // B chunks per k-iter (16 or 8)
    __shared__ __align__(16) unsigned short Al[2 * 128 * 32];   // 16 KB
    __shared__ __align__(16) unsigned short Bl[2 * NT * 32];

    const int tid  = threadIdx.x;
    const int lane = tid & 63;
    const int wid  = tid >> 6;
    const int wm   = wid >> 1;
    const int wn   = wid & 1;
    const int ln   = lane & 15;
    const int q    = lane >> 4;
    const int mblk = blockIdx.y * 128;
    const int nblk = blockIdx.x * NT;
    const int srow = lane >> 2;                  // 0..15 rows within chunk
    const int spart = lane & 3;                  // 16B part within 64B k-half

    const int kbeg = SPLITK2 ? blockIdx.z * (K / 2) : 0;
    const int kend = SPLITK2 ? kbeg + K / 2 : K;

    f32x4 acc[4][NTW] = {};

    for (int k0 = kbeg; k0 < kend; k0 += 64) {
        #pragma unroll
        for (int h = 0; h < 4; ++h) {
            int j = wid * 4 + h;
            int kh = j & 1, rb = j >> 1;
            int row = rb * 16 + srow;
            gl_lds16(A + (size_t)(mblk + row) * K + k0 + kh * 32 + spart * 8,
                     Al + kh * 4096 + rb * 512);
        }
        #pragma unroll
        for (int h = 0; h < BCH / 4; ++h) {
            int j = wid * (BCH / 4) + h;
            int kh = j & 1, rb = j >> 1;         // rb in [0, NT/16)
            int row = rb * 16 + srow;
            gl_lds16(Bw + (size_t)(nblk + row) * K + k0 + kh * 32 + spart * 8,
                     Bl + kh * (NT * 32) + rb * 512);
        }
        __syncthreads();

        #pragma unroll
        for (int kh = 0; kh < 2; ++kh) {
            bf16x8 af[4], bfr[NTW];
            #pragma unroll
            for (int mt = 0; mt < 4; ++mt)
                af[mt] = *(const bf16x8*)(Al + kh * 4096 + (wm * 64 + mt * 16 + ln) * 32 + q * 8);
            #pragma unroll
            for (int nt = 0; nt < NTW; ++nt)
                bfr[nt] = *(const bf16x8*)(Bl + kh * (NT * 32) + (wn * (NT/2) + nt * 16 + ln) * 32 + q * 8);
            #pragma unroll
            for (int mt = 0; mt < 4; ++mt)
                #pragma unroll
                for (int nt = 0; nt < NTW; ++nt)
                    acc[mt][nt] = __builtin_amdgcn_mfma_f32_16x16x32_bf16(
                        af[mt], bfr[nt], acc[mt][nt], 0, 0, 0);
        }
        __syncthreads();
    }

    const size_t cofs = SPLITK2 ? (size_t)blockIdx.z * M * N : 0;
    #pragma unroll
    for (int mt = 0; mt < 4; ++mt) {
        #pragma unroll
        for (int nt = 0; nt < NTW; ++nt) {
            int col = nblk + wn * (NT/2) + nt * 16 + ln;
            #pragma unroll
            for (int r = 0; r < 4; ++r) {
                int row = mblk + wm * 64 + mt * 16 + q * 4 + r;
                if (OM == OM_BF16)
                    ((unsigned short*)Cv)[(size_t)row * N + col] = f2bf(acc[mt][nt][r]);
                else
                    ((float*)Cv)[cofs + (size_t)row * N + col] = acc[mt][nt][r];
            }
        }
    }
}

// gemm2 split-K reduce: out = p0 + p1 + bias
__global__ void splitk_reduce_kernel(const float* __restrict__ part,
                                     const float* __restrict__ bias,
                                     float* __restrict__ out) {
    int i = (blockIdx.x * 256 + threadIdx.x) * 4;
    int n = i & (D_MODEL - 1);
    float4 a = *(const float4*)(part + i);
    float4 b = *(const float4*)(part + (size_t)MROWS * D_MODEL + i);
    float4 bv = *(const float4*)(bias + n);
    float4 o;
    o.x = a.x + b.x + bv.x; o.y = a.y + b.y + bv.y;
    o.z = a.z + b.z + bv.z; o.w = a.w + b.w + bv.w;
    *(float4*)(out + i) = o;
}

// ---------------- causal depthwise conv (k=4) + silu -> bf16 u -----------------
__global__ void conv_silu_kernel(const unsigned short* __restrict__ xzb,
                                 const float* __restrict__ conv_w,
                                 unsigned short* __restrict__ ub) {
    int idx = blockIdx.x * blockDim.x + threadIdx.x;   // m*2048 + d
    int d = idx & (D_INNER - 1);
    int m = idx >> 11;
    int l = m & (SEQ - 1);
    const float* w = conv_w + d * 4;
    float s = 0.f;
    #pragma unroll
    for (int j = 0; j < 4; ++j) {
        if (l - j >= 0) s += w[3 - j] * bf2f(xzb[(size_t)(m - j) * 4096 + d]);
    }
    float sig = 1.f / (1.f + __expf(-s));
    ub[idx] = f2bf(s * sig);
}

// ---------------- xproj mini-GEMM: part[ks][m][n] = ub[m,ks-slice] @ wbp^T -----
__global__ void xproj_mfma_kernel(const unsigned short* __restrict__ ub,
                                  const unsigned short* __restrict__ wbp,
                                  float* __restrict__ part) {
    __shared__ __align__(16) unsigned short Al[64 * 64];  // 8KB
    __shared__ __align__(16) unsigned short Bl[32 * 64];  // 4KB

    const int tid  = threadIdx.x;
    const int lane = tid & 63;
    const int wid  = tid >> 6;
    const int ln   = lane & 15;
    const int q    = lane >> 4;
    const int m0   = blockIdx.y * 64;
    const int ks   = blockIdx.x;
    const int srow = lane >> 3;
    const int spart = lane & 7;

    f32x4 acc[2] = {};

    for (int it = 0; it < 4; ++it) {
        int k0 = ks * XKC + it * 64;
        #pragma unroll
        for (int h = 0; h < 2; ++h) {
            int j = wid * 2 + h;
            int row = j * 8 + srow;
            gl_lds16(ub + (size_t)(m0 + row) * D_INNER + k0 + spart * 8, Al + j * 512);
        }
        {
            int row = wid * 8 + srow;
            gl_lds16(wbp + (size_t)row * D_INNER + k0 + spart * 8, Bl + wid * 512);
        }
        __syncthreads();

        bf16x8 af[2], bfr[2][2];
        #pragma unroll
        for (int kh = 0; kh < 2; ++kh) {
            af[kh] = *(const bf16x8*)(Al + (wid * 16 + ln) * 64 + kh * 32 + q * 8);
            bfr[0][kh] = *(const bf16x8*)(Bl + (0 * 16 + ln) * 64 + kh * 32 + q * 8);
            bfr[1][kh] = *(const bf16x8*)(Bl + (1 * 16 + ln) * 64 + kh * 32 + q * 8);
        }
        #pragma unroll
        for (int kh = 0; kh < 2; ++kh) {
            acc[0] = __builtin_amdgcn_mfma_f32_16x16x32_bf16(af[kh], bfr[0][kh], acc[0], 0, 0, 0);
            acc[1] = __builtin_amdgcn_mfma_f32_16x16x32_bf16(af[kh], bfr[1][kh], acc[1], 0, 0, 0);
        }
        __syncthreads();
    }

    #pragma unroll
    for (int nf = 0; nf < 2; ++nf) {
        #pragma unroll
        for (int r = 0; r < 4; ++r) {
            int m = m0 + wid * 16 + q * 4 + r;
            part[((size_t)ks * MROWS + m) * 32 + nf * 16 + ln] = acc[nf][r];
        }
    }
}

// ---------------- fused cooperative scan (A + B + C in one kernel) -------------
__device__ __forceinline__ float softplus_f(float xv) {
    return fmaxf(xv, 0.f) + __logf(1.f + __expf(-fabsf(xv)));
}

// grid (8, NCH, BATCH) = 512 blocks x 256 thr (2 blocks/CU — co-resident).
// Phase A: per-chunk local scan -> Pg,Sg. grid.sync.
// Phase B: 65536 serial chunk-combines -> Hin. grid.sync.
// Phase C: replay with Hin + ypost fusion. sdt/sB (LDS) and aA/dtw/dtb/Dv
// (registers) persist across the grid syncs — no re-reduce, no reload.
__global__ void scan_fused_kernel(const float* __restrict__ xpt,
                                  const float* __restrict__ dt_w,
                                  const float* __restrict__ dt_b,
                                  const float* __restrict__ A_param,
                                  const unsigned short* __restrict__ ub,
                                  const unsigned short* __restrict__ xzb,
                                  const float* __restrict__ Dp,
                                  float* __restrict__ Pg,
                                  float* __restrict__ Sg,
                                  float* __restrict__ Hin,
                                  unsigned short* __restrict__ ypb) {
    __shared__ float sdt[TCH];
    __shared__ float sB[TCH * D_STATE];
    const int tid = threadIdx.x;
    const int b = blockIdx.z, c = blockIdx.y;
    const int d = blockIdx.x * 256 + tid;
    const int mg0 = b * SEQ + c * TCH;

    // inline xproj-partial reduce for this chunk's rows
    for (int idx = tid; idx < TCH * 17; idx += 256) {
        int t = idx / 17, j = idx % 17;
        float s = 0.f;
        #pragma unroll
        for (int ks = 0; ks < XKS; ++ks)
            s += xpt[((size_t)ks * MROWS + mg0 + t) * 32 + j];
        if (j == 0) sdt[t] = s;
        else        sB[t * D_STATE + (j - 1)] = s;
    }
    __syncthreads();

    const float dtw = dt_w[d], dtb = dt_b[d];
    const float Dv = Dp[d];
    float aA[D_STATE], h[D_STATE];
    #pragma unroll
    for (int n4 = 0; n4 < 4; ++n4) {
        float4 ap = ((const float4*)(A_param + (size_t)d * D_STATE))[n4];
        aA[n4*4+0] = -__expf(ap.x); aA[n4*4+1] = -__expf(ap.y);
        aA[n4*4+2] = -__expf(ap.z); aA[n4*4+3] = -__expf(ap.w);
    }

    // ---- phase A: local scan with h0 = 0 ----
    #pragma unroll
    for (int n = 0; n < D_STATE; ++n) h[n] = 0.f;
    float tsum = 0.f;
    for (int t = 0; t < TCH; ++t) {
        float sp = softplus_f(sdt[t] * dtw + dtb);
        tsum += sp;
        #pragma unroll
        for (int n = 0; n < D_STATE; ++n) {
            float a = __expf(aA[n] * sp);
            h[n] = a * h[n] + sp * sB[t * D_STATE + n];
        }
    }
    size_t base = (size_t)c * NREC + ((size_t)(b * D_INNER + d)) * D_STATE;
    #pragma unroll
    for (int n4 = 0; n4 < 4; ++n4) {
        float4 pv, sv;
        pv.x = __expf(aA[n4*4+0] * tsum); pv.y = __expf(aA[n4*4+1] * tsum);
        pv.z = __expf(aA[n4*4+2] * tsum); pv.w = __expf(aA[n4*4+3] * tsum);
        sv.x = h[n4*4+0]; sv.y = h[n4*4+1]; sv.z = h[n4*4+2]; sv.w = h[n4*4+3];
        *(float4*)(Pg + base + n4 * 4) = pv;
        *(float4*)(Sg + base + n4 * 4) = sv;
    }

    cg::this_grid().sync();

    // ---- phase B: serial combine over chunks (first NREC threads) ----
    {
        int fb = (blockIdx.z * gridDim.y + blockIdx.y) * gridDim.x + blockIdx.x;
        int gid = fb * 256 + tid;                 // 0..131071
        if (gid < NREC) {
            float hh = 0.f;
            #pragma unroll
            for (int cc = 0; cc < NCH; ++cc) {
                size_t o = (size_t)cc * NREC + gid;
                Hin[o] = hh;
                hh = Pg[o] * hh + Sg[o];
            }
        }
    }

    cg::this_grid().sync();

    // ---- phase C: replay with h_in, fused ypost ----
    #pragma unroll
    for (int n4 = 0; n4 < 4; ++n4) {
        float4 hv = *(const float4*)(Hin + base + n4 * 4);
        h[n4*4+0] = hv.x; h[n4*4+1] = hv.y; h[n4*4+2] = hv.z; h[n4*4+3] = hv.w;
    }
    for (int t = 0; t < TCH; ++t) {
        float sp = softplus_f(sdt[t] * dtw + dtb);
        float y0 = 0.f, y1 = 0.f, y2 = 0.f, y3 = 0.f;
        #pragma unroll
        for (int n4 = 0; n4 < 4; ++n4) {
            #pragma unroll
            for (int j = 0; j < 4; ++j) {
                int n = n4 * 4 + j;
                float Bv = sB[t * D_STATE + n];
                float a = __expf(aA[n] * sp);
                h[n] = a * h[n] + sp * Bv;
                float p = h[n] * Bv;
                if (n4 == 0) y0 += p; else if (n4 == 1) y1 += p;
                else if (n4 == 2) y2 += p; else y3 += p;
            }
        }
        float y = (y0 + y1) + (y2 + y3);
        size_t m = (size_t)mg0 + t;
        float z  = bf2f(xzb[m * 4096 + D_INNER + d]);
        float sz = z / (1.f + __expf(-z));
        float uv = bf2f(ub[m * D_INNER + d]);
        ypb[m * D_INNER + d] = f2bf((y + uv * Dv) * sz);
    }
}

// ---------------- launch -------------------------------------------------------
extern "C" void kernel_launch(void* const* d_in, const int* in_sizes, int n_in,
                              void* d_out, int out_size, void* d_ws, size_t ws_size,
                              hipStream_t stream) {
    const float* x         = (const float*)d_in[0];
    const float* in_proj_w = (const float*)d_in[1];
    const float* conv_w    = (const float*)d_in[2];
    const float* x_proj_w  = (const float*)d_in[3];
    const float* dt_w      = (const float*)d_in[4];
    const float* dt_b      = (const float*)d_in[5];
    const float* A_param   = (const float*)d_in[6];
    const float* D_param   = (const float*)d_in[7];
    const float* out_w     = (const float*)d_in[8];
    const float* out_b     = (const float*)d_in[9];
    float* out = (float*)d_out;

    // workspace layout — all regions disjoint (92 MB)
    char* ws = (char*)d_ws;
    unsigned short* xb  = (unsigned short*)(ws);                      //  4 MB
    unsigned short* wbi = (unsigned short*)(ws + (4u  << 20));        //  8 MB
    unsigned short* wbo = (unsigned short*)(ws + (12u << 20));        //  4 MB
    unsigned short* xzb = (unsigned short*)(ws + (16u << 20));        // 16 MB (bf16)
    unsigned short* ub  = (unsigned short*)(ws + (32u << 20));        //  8 MB
    unsigned short* wbp = (unsigned short*)(ws + (40u << 20));        // 128 KB
    float*          xpt = (float*)(ws + (40u << 20) + (512u << 10));  //  2 MB
    float*          Pg  = (float*)(ws + (44u << 20));                 //  8 MB
    float*          Sg  = (float*)(ws + (52u << 20));                 //  8 MB
    float*          Hin = (float*)(ws + (60u << 20));                 //  8 MB
    unsigned short* ypb = (unsigned short*)(ws + (68u << 20));        //  8 MB
    float*          g2p = (float*)(ws + (76u << 20));                 // 16 MB partials

    // 1) fp32 -> bf16 conversions
    cvt_all_kernel<<<dim3(8448), 256, 0, stream>>>(
        x, in_proj_w, out_w, x_proj_w, xb, wbi, wbo, wbp);

    // 2) xz = x @ in_proj_w^T -> bf16 (M=2048, N=4096, K=1024)
    gemm_bf16_kernel<128, false, OM_BF16><<<dim3(32, 16), 256, 0, stream>>>(
        xb, wbi, xzb, MROWS, 2 * D_INNER, D_MODEL);

    // 3) u = silu(causal_conv(xz[:, :2048])) -> bf16
    conv_silu_kernel<<<dim3(MROWS * D_INNER / 256), 256, 0, stream>>>(xzb, conv_w, ub);

    // 4) x_dbl partials = u @ x_proj_w^T (k-split MFMA) -> xpt
    xproj_mfma_kernel<<<dim3(XKS, MROWS / 64), 256, 0, stream>>>(ub, wbp, xpt);

    // 5) fused cooperative scan (A+B+C, two grid syncs) -> ypb
    {
        void* args[] = { (void*)&xpt, (void*)&dt_w, (void*)&dt_b, (void*)&A_param,
                         (void*)&ub, (void*)&xzb, (void*)&D_param,
                         (void*)&Pg, (void*)&Sg, (void*)&Hin, (void*)&ypb };
        hipLaunchCooperativeKernel((const void*)scan_fused_kernel,
                                   dim3(D_INNER / 256, NCH, BATCH), dim3(256),
                                   args, 0, stream);
    }

    // 6) out partials = yp @ out_w^T (M=2048, N=1024, K=2048 split 2)
    gemm_bf16_kernel<64, true, OM_F32><<<dim3(1024 / 64, MROWS / 128, 2), 256, 0, stream>>>(
        ypb, wbo, g2p, MROWS, D_MODEL, D_INNER);

    // 7) out = p0 + p1 + out_b
    splitk_reduce_kernel<<<dim3(MROWS * D_MODEL / 1024), 256, 0, stream>>>(g2p, out_b, out);
}

// Round 10
// 224.113 us; speedup vs baseline: 1.5336x; 1.5336x over previous
//
#include <hip/hip_runtime.h>
#include <stdint.h>
#include <stddef.h>

#define D_MODEL 1024
#define D_STATE 16
#define D_INNER 2048
#define BATCH   2
#define SEQ     1024
#define MROWS   (BATCH*SEQ)   // 2048

// chunked scan config
#define NCH 32
#define TCH (SEQ/NCH)         // 32
#define NREC (BATCH*D_INNER*D_STATE)  // 65536

// xproj k-split
#define XKS 8
#define XKC (D_INNER/XKS)     // 256

// gemm output modes
#define OM_BF16   0
#define OM_F32    1

typedef __bf16 bf16x8 __attribute__((ext_vector_type(8)));
typedef float  f32x4  __attribute__((ext_vector_type(4)));

__device__ __forceinline__ unsigned short f2bf(float f) {
    unsigned int u = __float_as_uint(f);
    u += 0x7fffu + ((u >> 16) & 1u);      // RNE
    return (unsigned short)(u >> 16);
}
__device__ __forceinline__ float bf2f(unsigned short v) {
    return __uint_as_float((unsigned int)v << 16);
}

// async global -> LDS, 16B/lane. Global addr is PER-LANE (gather); LDS dest is
// wave-uniform base + lane*16 (m104/m108).
__device__ __forceinline__ void gl_lds16(const unsigned short* g, unsigned short* l) {
    __builtin_amdgcn_global_load_lds(
        (const __attribute__((address_space(1))) unsigned int*)g,
        (__attribute__((address_space(3))) unsigned int*)l, 16, 0, 0);
}

// ---------------- fused fp32 -> bf16 conversions -------------------------------
__global__ void cvt_all_kernel(const float* __restrict__ x,
                               const float* __restrict__ w1,
                               const float* __restrict__ w2,
                               const float* __restrict__ xw,
                               unsigned short* __restrict__ xb,
                               unsigned short* __restrict__ wbi,
                               unsigned short* __restrict__ wbo,
                               unsigned short* __restrict__ wbp) {
    int blk = blockIdx.x, tid = threadIdx.x;
    if (blk < 8192) {
        const float* src; unsigned short* dst; int i;
        if (blk < 2048)      { src = x;  dst = xb;  i = blk * 1024 + tid * 4; }
        else if (blk < 6144) { src = w1; dst = wbi; i = (blk - 2048) * 1024 + tid * 4; }
        else                 { src = w2; dst = wbo; i = (blk - 6144) * 1024 + tid * 4; }
        float4 v = *(const float4*)(src + i);
        ushort4 o;
        o.x = f2bf(v.x); o.y = f2bf(v.y); o.z = f2bf(v.z); o.w = f2bf(v.w);
        *(ushort4*)(dst + i) = o;
    } else {
        int id = (blk - 8192) * 256 + tid;          // 0..65535
        wbp[id] = (id < 17 * D_INNER) ? f2bf(xw[id]) : (unsigned short)0;
    }
}

// ---------------- bf16 MFMA GEMM, BK=64 dual-panel LDS -------------------------
// C[m,n] = sum_k A[m,k]*Bw[n,k]. Tile 128 x NT, 256 thr (4 waves 2x2).
// A: 16 chunks/iter, B: NT/8 chunks/iter. SPLITK2: gridDim.z==2, partials.
// Session lessons baked in:
//  R7: atomic split-K combine on d_out cost ~10us — partials+reduce wins.
//  R8: XCD supertile swizzle neutral-to-negative (operands L3-resident) — out.
//  R9: cooperative grid.sync costs ~80us/sync on gfx950 — kernel boundaries
//      are the cheap grid barrier; never fuse across one for <10us of savings.
template<int NT, bool SPLITK2, int OM>
__global__ void gemm_bf16_kernel(const unsigned short* __restrict__ A,
                                 const unsigned short* __restrict__ Bw,
                                 void* __restrict__ Cv,
                                 int M, int N, int K) {
    constexpr int NTW = NT / 32;                 // n-frags per wave (4 or 2)
    constexpr int BCH = NT / 8;                  // B chunks per k-iter (16 or 8)
    __shared__ __align__(16) unsigned short Al[2 * 128 * 32];   // 16 KB
    __shared__ __align__(16) unsigned short Bl[2 * NT * 32];

    const int tid  = threadIdx.x;
    const int lane = tid & 63;
    const int wid  = tid >> 6;
    const int wm   = wid >> 1;
    const int wn   = wid & 1;
    const int ln   = lane & 15;
    const int q    = lane >> 4;
    const int mblk = blockIdx.y * 128;
    const int nblk = blockIdx.x * NT;
    const int srow = lane >> 2;                  // 0..15 rows within chunk
    const int spart = lane & 3;                  // 16B part within 64B k-half

    const int kbeg = SPLITK2 ? blockIdx.z * (K / 2) : 0;
    const int kend = SPLITK2 ? kbeg + K / 2 : K;

    f32x4 acc[4][NTW] = {};

    for (int k0 = kbeg; k0 < kend; k0 += 64) {
        #pragma unroll
        for (int h = 0; h < 4; ++h) {
            int j = wid * 4 + h;
            int kh = j & 1, rb = j >> 1;
            int row = rb * 16 + srow;
            gl_lds16(A + (size_t)(mblk + row) * K + k0 + kh * 32 + spart * 8,
                     Al + kh * 4096 + rb * 512);
        }
        #pragma unroll
        for (int h = 0; h < BCH / 4; ++h) {
            int j = wid * (BCH / 4) + h;
            int kh = j & 1, rb = j >> 1;         // rb in [0, NT/16)
            int row = rb * 16 + srow;
            gl_lds16(Bw + (size_t)(nblk + row) * K + k0 + kh * 32 + spart * 8,
                     Bl + kh * (NT * 32) + rb * 512);
        }
        __syncthreads();

        #pragma unroll
        for (int kh = 0; kh < 2; ++kh) {
            bf16x8 af[4], bfr[NTW];
            #pragma unroll
            for (int mt = 0; mt < 4; ++mt)
                af[mt] = *(const bf16x8*)(Al + kh * 4096 + (wm * 64 + mt * 16 + ln) * 32 + q * 8);
            #pragma unroll
            for (int nt = 0; nt < NTW; ++nt)
                bfr[nt] = *(const bf16x8*)(Bl + kh * (NT * 32) + (wn * (NT/2) + nt * 16 + ln) * 32 + q * 8);
            #pragma unroll
            for (int mt = 0; mt < 4; ++mt)
                #pragma unroll
                for (int nt = 0; nt < NTW; ++nt)
                    acc[mt][nt] = __builtin_amdgcn_mfma_f32_16x16x32_bf16(
                        af[mt], bfr[nt], acc[mt][nt], 0, 0, 0);
        }
        __syncthreads();
    }

    const size_t cofs = SPLITK2 ? (size_t)blockIdx.z * M * N : 0;
    #pragma unroll
    for (int mt = 0; mt < 4; ++mt) {
        #pragma unroll
        for (int nt = 0; nt < NTW; ++nt) {
            int col = nblk + wn * (NT/2) + nt * 16 + ln;
            #pragma unroll
            for (int r = 0; r < 4; ++r) {
                int row = mblk + wm * 64 + mt * 16 + q * 4 + r;
                if (OM == OM_BF16)
                    ((unsigned short*)Cv)[(size_t)row * N + col] = f2bf(acc[mt][nt][r]);
                else
                    ((float*)Cv)[cofs + (size_t)row * N + col] = acc[mt][nt][r];
            }
        }
    }
}

// gemm2 split-K reduce: out = p0 + p1 + bias
__global__ void splitk_reduce_kernel(const float* __restrict__ part,
                                     const float* __restrict__ bias,
                                     float* __restrict__ out) {
    int i = (blockIdx.x * 256 + threadIdx.x) * 4;
    int n = i & (D_MODEL - 1);
    float4 a = *(const float4*)(part + i);
    float4 b = *(const float4*)(part + (size_t)MROWS * D_MODEL + i);
    float4 bv = *(const float4*)(bias + n);
    float4 o;
    o.x = a.x + b.x + bv.x; o.y = a.y + b.y + bv.y;
    o.z = a.z + b.z + bv.z; o.w = a.w + b.w + bv.w;
    *(float4*)(out + i) = o;
}

// ---------------- causal depthwise conv (k=4) + silu -> bf16 u -----------------
__global__ void conv_silu_kernel(const unsigned short* __restrict__ xzb,
                                 const float* __restrict__ conv_w,
                                 unsigned short* __restrict__ ub) {
    int idx = blockIdx.x * blockDim.x + threadIdx.x;   // m*2048 + d
    int d = idx & (D_INNER - 1);
    int m = idx >> 11;
    int l = m & (SEQ - 1);
    const float* w = conv_w + d * 4;
    float s = 0.f;
    #pragma unroll
    for (int j = 0; j < 4; ++j) {
        if (l - j >= 0) s += w[3 - j] * bf2f(xzb[(size_t)(m - j) * 4096 + d]);
    }
    float sig = 1.f / (1.f + __expf(-s));
    ub[idx] = f2bf(s * sig);
}

// ---------------- xproj mini-GEMM: part[ks][m][n] = ub[m,ks-slice] @ wbp^T -----
__global__ void xproj_mfma_kernel(const unsigned short* __restrict__ ub,
                                  const unsigned short* __restrict__ wbp,
                                  float* __restrict__ part) {
    __shared__ __align__(16) unsigned short Al[64 * 64];  // 8KB
    __shared__ __align__(16) unsigned short Bl[32 * 64];  // 4KB

    const int tid  = threadIdx.x;
    const int lane = tid & 63;
    const int wid  = tid >> 6;
    const int ln   = lane & 15;
    const int q    = lane >> 4;
    const int m0   = blockIdx.y * 64;
    const int ks   = blockIdx.x;
    const int srow = lane >> 3;
    const int spart = lane & 7;

    f32x4 acc[2] = {};

    for (int it = 0; it < 4; ++it) {
        int k0 = ks * XKC + it * 64;
        #pragma unroll
        for (int h = 0; h < 2; ++h) {
            int j = wid * 2 + h;
            int row = j * 8 + srow;
            gl_lds16(ub + (size_t)(m0 + row) * D_INNER + k0 + spart * 8, Al + j * 512);
        }
        {
            int row = wid * 8 + srow;
            gl_lds16(wbp + (size_t)row * D_INNER + k0 + spart * 8, Bl + wid * 512);
        }
        __syncthreads();

        bf16x8 af[2], bfr[2][2];
        #pragma unroll
        for (int kh = 0; kh < 2; ++kh) {
            af[kh] = *(const bf16x8*)(Al + (wid * 16 + ln) * 64 + kh * 32 + q * 8);
            bfr[0][kh] = *(const bf16x8*)(Bl + (0 * 16 + ln) * 64 + kh * 32 + q * 8);
            bfr[1][kh] = *(const bf16x8*)(Bl + (1 * 16 + ln) * 64 + kh * 32 + q * 8);
        }
        #pragma unroll
        for (int kh = 0; kh < 2; ++kh) {
            acc[0] = __builtin_amdgcn_mfma_f32_16x16x32_bf16(af[kh], bfr[0][kh], acc[0], 0, 0, 0);
            acc[1] = __builtin_amdgcn_mfma_f32_16x16x32_bf16(af[kh], bfr[1][kh], acc[1], 0, 0, 0);
        }
        __syncthreads();
    }

    #pragma unroll
    for (int nf = 0; nf < 2; ++nf) {
        #pragma unroll
        for (int r = 0; r < 4; ++r) {
            int m = m0 + wid * 16 + q * 4 + r;
            part[((size_t)ks * MROWS + m) * 32 + nf * 16 + ln] = acc[nf][r];
        }
    }
}

// ---------------- chunked selective scan ---------------------------------------
__device__ __forceinline__ float softplus_f(float xv) {
    return fmaxf(xv, 0.f) + __logf(1.f + __expf(-fabsf(xv)));
}

// reduce xpt partials for this chunk's rows into sdt/sB (inline xproj reduce)
__device__ __forceinline__ void reduce_xpt(const float* __restrict__ xpt,
                                           int mg0, int tid,
                                           float* sdt, float* sB) {
    for (int idx = tid; idx < TCH * 17; idx += 256) {
        int t = idx / 17, j = idx % 17;
        float s = 0.f;
        #pragma unroll
        for (int ks = 0; ks < XKS; ++ks)
            s += xpt[((size_t)ks * MROWS + mg0 + t) * 32 + j];
        if (j == 0) sdt[t] = s;
        else        sB[t * D_STATE + (j - 1)] = s;
    }
}

__global__ void scanA_kernel(const float* __restrict__ xpt,
                             const float* __restrict__ dt_w,
                             const float* __restrict__ dt_b,
                             const float* __restrict__ A_param,
                             float* __restrict__ Pg,
                             float* __restrict__ Sg) {
    __shared__ float sdt[TCH];
    __shared__ float sB[TCH * D_STATE];
    const int tid = threadIdx.x;
    const int b = blockIdx.z, c = blockIdx.y;
    const int d = blockIdx.x * 256 + tid;
    const int mg0 = b * SEQ + c * TCH;

    reduce_xpt(xpt, mg0, tid, sdt, sB);
    __syncthreads();

    const float dtw = dt_w[d], dtb = dt_b[d];
    float aA[D_STATE], h[D_STATE];
    #pragma unroll
    for (int n4 = 0; n4 < 4; ++n4) {
        float4 ap = ((const float4*)(A_param + (size_t)d * D_STATE))[n4];
        aA[n4*4+0] = -__expf(ap.x); aA[n4*4+1] = -__expf(ap.y);
        aA[n4*4+2] = -__expf(ap.z); aA[n4*4+3] = -__expf(ap.w);
    }
    #pragma unroll
    for (int n = 0; n < D_STATE; ++n) h[n] = 0.f;
    float tsum = 0.f;

    for (int t = 0; t < TCH; ++t) {
        float sp = softplus_f(sdt[t] * dtw + dtb);
        tsum += sp;
        #pragma unroll
        for (int n = 0; n < D_STATE; ++n) {
            float a = __expf(aA[n] * sp);
            h[n] = a * h[n] + sp * sB[t * D_STATE + n];
        }
    }

    size_t base = (size_t)c * NREC + ((size_t)(b * D_INNER + d)) * D_STATE;
    #pragma unroll
    for (int n4 = 0; n4 < 4; ++n4) {
        float4 pv, sv;
        pv.x = __expf(aA[n4*4+0] * tsum); pv.y = __expf(aA[n4*4+1] * tsum);
        pv.z = __expf(aA[n4*4+2] * tsum); pv.w = __expf(aA[n4*4+3] * tsum);
        sv.x = h[n4*4+0]; sv.y = h[n4*4+1]; sv.z = h[n4*4+2]; sv.w = h[n4*4+3];
        *(float4*)(Pg + base + n4 * 4) = pv;
        *(float4*)(Sg + base + n4 * 4) = sv;
    }
}

__global__ void scanB_kernel(const float* __restrict__ Pg,
                             const float* __restrict__ Sg,
                             float* __restrict__ Hin) {
    int idx = blockIdx.x * 256 + threadIdx.x;
    float h = 0.f;
    #pragma unroll
    for (int c = 0; c < NCH; ++c) {
        size_t o = (size_t)c * NREC + idx;
        Hin[o] = h;
        h = Pg[o] * h + Sg[o];
    }
}

// scanC: fused ypost (yp = (y + u*D)*silu(z) -> bf16)
__global__ void scanC_kernel(const float* __restrict__ xpt,
                             const float* __restrict__ dt_w,
                             const float* __restrict__ dt_b,
                             const float* __restrict__ A_param,
                             const float* __restrict__ Hin,
                             const unsigned short* __restrict__ ub,
                             const unsigned short* __restrict__ xzb,
                             const float* __restrict__ Dp,
                             unsigned short* __restrict__ ypb) {
    __shared__ float sdt[TCH];
    __shared__ float sB[TCH * D_STATE];
    const int tid = threadIdx.x;
    const int b = blockIdx.z, c = blockIdx.y;
    const int d = blockIdx.x * 256 + tid;
    const int mg0 = b * SEQ + c * TCH;

    reduce_xpt(xpt, mg0, tid, sdt, sB);
    __syncthreads();

    const float dtw = dt_w[d], dtb = dt_b[d];
    const float Dv = Dp[d];
    float aA[D_STATE], h[D_STATE];
    #pragma unroll
    for (int n4 = 0; n4 < 4; ++n4) {
        float4 ap = ((const float4*)(A_param + (size_t)d * D_STATE))[n4];
        aA[n4*4+0] = -__expf(ap.x); aA[n4*4+1] = -__expf(ap.y);
        aA[n4*4+2] = -__expf(ap.z); aA[n4*4+3] = -__expf(ap.w);
    }
    size_t hbase = (size_t)c * NREC + ((size_t)(b * D_INNER + d)) * D_STATE;
    #pragma unroll
    for (int n4 = 0; n4 < 4; ++n4) {
        float4 hv = *(const float4*)(Hin + hbase + n4 * 4);
        h[n4*4+0] = hv.x; h[n4*4+1] = hv.y; h[n4*4+2] = hv.z; h[n4*4+3] = hv.w;
    }

    for (int t = 0; t < TCH; ++t) {
        float sp = softplus_f(sdt[t] * dtw + dtb);
        float y0 = 0.f, y1 = 0.f, y2 = 0.f, y3 = 0.f;
        #pragma unroll
        for (int n4 = 0; n4 < 4; ++n4) {
            #pragma unroll
            for (int j = 0; j < 4; ++j) {
                int n = n4 * 4 + j;
                float Bv = sB[t * D_STATE + n];
                float a = __expf(aA[n] * sp);
                h[n] = a * h[n] + sp * Bv;
                float p = h[n] * Bv;
                if (n4 == 0) y0 += p; else if (n4 == 1) y1 += p;
                else if (n4 == 2) y2 += p; else y3 += p;
            }
        }
        float y = (y0 + y1) + (y2 + y3);
        size_t m = (size_t)mg0 + t;
        float z  = bf2f(xzb[m * 4096 + D_INNER + d]);
        float sz = z / (1.f + __expf(-z));
        float uv = bf2f(ub[m * D_INNER + d]);
        ypb[m * D_INNER + d] = f2bf((y + uv * Dv) * sz);
    }
}

// ---------------- launch -------------------------------------------------------
extern "C" void kernel_launch(void* const* d_in, const int* in_sizes, int n_in,
                              void* d_out, int out_size, void* d_ws, size_t ws_size,
                              hipStream_t stream) {
    const float* x         = (const float*)d_in[0];
    const float* in_proj_w = (const float*)d_in[1];
    const float* conv_w    = (const float*)d_in[2];
    const float* x_proj_w  = (const float*)d_in[3];
    const float* dt_w      = (const float*)d_in[4];
    const float* dt_b      = (const float*)d_in[5];
    const float* A_param   = (const float*)d_in[6];
    const float* D_param   = (const float*)d_in[7];
    const float* out_w     = (const float*)d_in[8];
    const float* out_b     = (const float*)d_in[9];
    float* out = (float*)d_out;

    // workspace layout — all regions disjoint (92 MB)
    char* ws = (char*)d_ws;
    unsigned short* xb  = (unsigned short*)(ws);                      //  4 MB
    unsigned short* wbi = (unsigned short*)(ws + (4u  << 20));        //  8 MB
    unsigned short* wbo = (unsigned short*)(ws + (12u << 20));        //  4 MB
    unsigned short* xzb = (unsigned short*)(ws + (16u << 20));        // 16 MB (bf16)
    unsigned short* ub  = (unsigned short*)(ws + (32u << 20));        //  8 MB
    unsigned short* wbp = (unsigned short*)(ws + (40u << 20));        // 128 KB
    float*          xpt = (float*)(ws + (40u << 20) + (512u << 10));  //  2 MB
    float*          Pg  = (float*)(ws + (44u << 20));                 //  8 MB
    float*          Sg  = (float*)(ws + (52u << 20));                 //  8 MB
    float*          Hin = (float*)(ws + (60u << 20));                 //  8 MB
    unsigned short* ypb = (unsigned short*)(ws + (68u << 20));        //  8 MB
    float*          g2p = (float*)(ws + (76u << 20));                 // 16 MB partials

    // 1) fp32 -> bf16 conversions
    cvt_all_kernel<<<dim3(8448), 256, 0, stream>>>(
        x, in_proj_w, out_w, x_proj_w, xb, wbi, wbo, wbp);

    // 2) xz = x @ in_proj_w^T -> bf16 (M=2048, N=4096, K=1024)
    gemm_bf16_kernel<128, false, OM_BF16><<<dim3(32, 16), 256, 0, stream>>>(
        xb, wbi, xzb, MROWS, 2 * D_INNER, D_MODEL);

    // 3) u = silu(causal_conv(xz[:, :2048])) -> bf16
    conv_silu_kernel<<<dim3(MROWS * D_INNER / 256), 256, 0, stream>>>(xzb, conv_w, ub);

    // 4) x_dbl partials = u @ x_proj_w^T (k-split MFMA) -> xpt
    xproj_mfma_kernel<<<dim3(XKS, MROWS / 64), 256, 0, stream>>>(ub, wbp, xpt);

    // 5) chunked selective scan (xpt reduced inline in scanA/scanC; scanC fuses
    //    ypost). Separate launches — kernel boundaries are the cheap barrier (R9).
    scanA_kernel<<<dim3(D_INNER / 256, NCH, BATCH), 256, 0, stream>>>(
        xpt, dt_w, dt_b, A_param, Pg, Sg);
    scanB_kernel<<<dim3(NREC / 256), 256, 0, stream>>>(Pg, Sg, Hin);
    scanC_kernel<<<dim3(D_INNER / 256, NCH, BATCH), 256, 0, stream>>>(
        xpt, dt_w, dt_b, A_param, Hin, ub, xzb, D_param, ypb);

    // 6) out partials = yp @ out_w^T (M=2048, N=1024, K=2048 split 2)
    gemm_bf16_kernel<64, true, OM_F32><<<dim3(1024 / 64, MROWS / 128, 2), 256, 0, stream>>>(
        ypb, wbo, g2p, MROWS, D_MODEL, D_INNER);

    // 7) out = p0 + p1 + out_b
    splitk_reduce_kernel<<<dim3(MROWS * D_MODEL / 1024), 256, 0, stream>>>(g2p, out_b, out);
}